// Round 2
// baseline (213.918 us; speedup 1.0000x reference)
//
#include <hip/hip_runtime.h>

// L1 attention: attn[b,s,t,h] = -sum_w |q[b,s,h,w] - k[b,t,h,w]| / sqrt(W)
// B=1, S=T=1024, H=8, W=32, fp32 in / fp32 out.
//
// Round 2 structure: thread = one (t,h); k-row (128B) register-resident,
// reused across the s loop. q-rows read from global per s (L1/L2-resident,
// 8-lane broadcast dedup). No LDS, no barriers, ~80 VGPR, 4 waves/SIMD.
// Block = 256 thr = 32 t x 8 h; grid = (32 t-tiles, 32 s-tiles) = 1024 blocks.

constexpr int S_DIM = 1024;
constexpr int T_DIM = 1024;
constexpr int H_DIM = 8;
constexpr int W_DIM = 32;
constexpr int TB = 32;   // t per block
constexpr int SB = 32;   // s per block

__global__ __launch_bounds__(256, 4)
void l1attn_kernel(const float* __restrict__ q,
                   const float* __restrict__ k,
                   float* __restrict__ out) {
    const int tid  = threadIdx.x;
    const int h    = tid & 7;
    const int tsub = tid >> 3;                 // 0..31
    const int t    = blockIdx.x * TB + tsub;
    const int s0   = blockIdx.y * SB;

    // ---- k row (t,h) -> 32 VGPRs, reused for all s ----
    float kreg[W_DIM];
    {
        const float4* krow = (const float4*)(k + (t * H_DIM + h) * W_DIM);
        #pragma unroll
        for (int j = 0; j < 8; ++j) {
            float4 v = krow[j];
            kreg[4 * j + 0] = v.x;
            kreg[4 * j + 1] = v.y;
            kreg[4 * j + 2] = v.z;
            kreg[4 * j + 3] = v.w;
        }
    }

    const float nscale = -0.17677669529663688f;  // -1/sqrt(32)

    #pragma unroll 2
    for (int si = 0; si < SB; ++si) {
        const int s = s0 + si;
        const float4* qrow = (const float4*)(q + (s * H_DIM + h) * W_DIM);
        float4 qv[8];
        #pragma unroll
        for (int j = 0; j < 8; ++j) qv[j] = qrow[j];   // issue all 8 loads

        float a0 = 0.f, a1 = 0.f, a2 = 0.f, a3 = 0.f;  // 4 chains for ILP
        #pragma unroll
        for (int j = 0; j < 8; ++j) {
            a0 += fabsf(qv[j].x - kreg[4 * j + 0]);
            a1 += fabsf(qv[j].y - kreg[4 * j + 1]);
            a2 += fabsf(qv[j].z - kreg[4 * j + 2]);
            a3 += fabsf(qv[j].w - kreg[4 * j + 3]);
        }
        out[(s * T_DIM + t) * H_DIM + h] = ((a0 + a1) + (a2 + a3)) * nscale;
    }
}

extern "C" void kernel_launch(void* const* d_in, const int* in_sizes, int n_in,
                              void* d_out, int out_size, void* d_ws, size_t ws_size,
                              hipStream_t stream) {
    const float* q = (const float*)d_in[0];
    const float* k = (const float*)d_in[1];
    float* out = (float*)d_out;
    dim3 grid(T_DIM / TB, S_DIM / SB);  // (32, 32) = 1024 blocks
    l1attn_kernel<<<grid, dim3(256, 1, 1), 0, stream>>>(q, k, out);
}

// Round 3
// 79.270 us; speedup vs baseline: 2.6986x; 2.6986x over previous
//
#include <hip/hip_runtime.h>

// L1 attention: attn[b,s,t,h] = -sum_w |q[b,s,h,w] - k[b,t,h,w]| / sqrt(W)
// B=1, S=T=1024, H=8, W=32, fp32 in / fp32 out.
//
// Round 3: main loop touches ONLY LDS + registers (no global-load latency).
// - thread = (h, tsub) owns TWO k rows (t0+tsub, t0+32+tsub) in 64 VGPRs.
// - q tile (16 s x 8 h x 128B = 16 KB) staged to LDS once, chunk-XOR swizzle
//   (j ^ h) -> broadcast reads conflict-free across all 32 banks.
// - 2 outputs per q-row read: LDS traffic 64B/output (537 MB total, ~45% of
//   LDS ceiling at the target runtime).
// - nontemporal output stores: the 32 MB write stream must not evict q/k
//   from L2 (R2's FETCH=24MB / 900cy-latency failure mode).

constexpr int S_DIM = 1024;
constexpr int T_DIM = 1024;
constexpr int H_DIM = 8;
constexpr int W_DIM = 32;
constexpr int TB = 64;   // t per block (2 per thread)
constexpr int SB = 16;   // s per block

__global__ __launch_bounds__(256, 4)
void l1attn_kernel(const float* __restrict__ q,
                   const float* __restrict__ k,
                   float* __restrict__ out) {
    const int tid  = threadIdx.x;
    const int h    = tid & 7;
    const int tsub = tid >> 3;                 // 0..31
    const int t0   = blockIdx.x * TB;
    const int s0   = blockIdx.y * SB;

    __shared__ float4 qlds[SB * H_DIM * (W_DIM / 4)];  // 1024 float4 = 16 KB

    // ---- two k rows -> 64 VGPRs, reused for all s ----
    float kreg[2][W_DIM];
    #pragma unroll
    for (int u = 0; u < 2; ++u) {
        const float4* krow =
            (const float4*)(k + ((t0 + u * 32 + tsub) * H_DIM + h) * W_DIM);
        #pragma unroll
        for (int j = 0; j < 8; ++j) {
            float4 v = krow[j];
            kreg[u][4 * j + 0] = v.x;
            kreg[u][4 * j + 1] = v.y;
            kreg[u][4 * j + 2] = v.z;
            kreg[u][4 * j + 3] = v.w;
        }
    }

    // ---- stage q tile (contiguous 16 KB) into swizzled LDS ----
    const float4* q4 = (const float4*)(q + (size_t)s0 * H_DIM * W_DIM);
    #pragma unroll
    for (int p = 0; p < 4; ++p) {
        int f = p * 256 + tid;   // float4 index, 0..1023
        int r = f >> 3;          // row = si*8 + h_row
        int j = f & 7;           // 16B chunk in row
        qlds[r * 8 + (j ^ (r & 7))] = q4[f];
    }
    __syncthreads();

    const float nscale = -0.17677669529663688f;  // -1/sqrt(32)

    for (int si = 0; si < SB; ++si) {
        const float4* qrow = qlds + (si * H_DIM + h) * 8;
        float4 qv[8];
        #pragma unroll
        for (int j = 0; j < 8; ++j) qv[j] = qrow[j ^ h];

        float a[2][4] = {{0.f, 0.f, 0.f, 0.f}, {0.f, 0.f, 0.f, 0.f}};
        #pragma unroll
        for (int j = 0; j < 8; ++j) {
            #pragma unroll
            for (int u = 0; u < 2; ++u) {
                a[u][0] += fabsf(qv[j].x - kreg[u][4 * j + 0]);
                a[u][1] += fabsf(qv[j].y - kreg[u][4 * j + 1]);
                a[u][2] += fabsf(qv[j].z - kreg[u][4 * j + 2]);
                a[u][3] += fabsf(qv[j].w - kreg[u][4 * j + 3]);
            }
        }
        const int s = s0 + si;
        const float r0 = ((a[0][0] + a[0][1]) + (a[0][2] + a[0][3])) * nscale;
        const float r1 = ((a[1][0] + a[1][1]) + (a[1][2] + a[1][3])) * nscale;
        __builtin_nontemporal_store(r0, &out[(s * T_DIM + t0 + tsub) * H_DIM + h]);
        __builtin_nontemporal_store(r1, &out[(s * T_DIM + t0 + 32 + tsub) * H_DIM + h]);
    }
}

extern "C" void kernel_launch(void* const* d_in, const int* in_sizes, int n_in,
                              void* d_out, int out_size, void* d_ws, size_t ws_size,
                              hipStream_t stream) {
    const float* q = (const float*)d_in[0];
    const float* k = (const float*)d_in[1];
    float* out = (float*)d_out;
    dim3 grid(T_DIM / TB, S_DIM / SB);  // (16, 64) = 1024 blocks
    l1attn_kernel<<<grid, dim3(256, 1, 1), 0, stream>>>(q, k, out);
}